// Round 17
// baseline (365.716 us; speedup 1.0000x reference)
//
#include <hip/hip_runtime.h>
#include <stdint.h>
#include <math.h>

#define NN 8192
#define DIM 64
#define KSEL 32
#define BK2 16
#define TILE 128
#define NTB (NN / TILE)          // 64 tiles per side
#define NTRI ((NTB * (NTB + 1)) / 2)   // 2080 upper-tri blocks

#define AS1 __attribute__((address_space(1)))
#define AS3 __attribute__((address_space(3)))

// ---- XLA/Eigen f32 tanh rational approximation (bit-exact emulation) ----
__device__ __forceinline__ float tanh_xla(float x) {
    const float kClamp = 7.90531110763549805f;
    float xc = fminf(fmaxf(x, -kClamp), kClamp);
    float x2 = xc * xc;
    float p = -2.76076847742355e-16f;
    p = fmaf(x2, p, 2.00018790482477e-13f);
    p = fmaf(x2, p, -8.60467152213735e-11f);
    p = fmaf(x2, p, 5.12229709037114e-08f);
    p = fmaf(x2, p, 1.48572235717979e-05f);
    p = fmaf(x2, p, 6.37261928875436e-04f);
    p = fmaf(x2, p, 4.89352455891786e-03f);
    p = xc * p;
    float q = 1.19825839466702e-06f;
    q = fmaf(x2, q, 1.18534705686654e-04f);
    q = fmaf(x2, q, 2.26843463243900e-03f);
    q = fmaf(x2, q, 4.89352518554385e-03f);
    float r = p / q;
    return (fabsf(x) < 0.0004f) ? x : r;
}
// positive-input variant (ax >= 0), same bits as tanh_xla(ax)
__device__ __forceinline__ float tanh_xla_pos(float ax) {
    const float kClamp = 7.90531110763549805f;
    float xc = fminf(ax, kClamp);
    float x2 = xc * xc;
    float p = -2.76076847742355e-16f;
    p = fmaf(x2, p, 2.00018790482477e-13f);
    p = fmaf(x2, p, -8.60467152213735e-11f);
    p = fmaf(x2, p, 5.12229709037114e-08f);
    p = fmaf(x2, p, 1.48572235717979e-05f);
    p = fmaf(x2, p, 6.37261928875436e-04f);
    p = fmaf(x2, p, 4.89352455891786e-03f);
    p = xc * p;
    float q = 1.19825839466702e-06f;
    q = fmaf(x2, q, 1.18534705686654e-04f);
    q = fmaf(x2, q, 2.26843463243900e-03f);
    q = fmaf(x2, q, 4.89352518554385e-03f);
    float r = p / q;
    return (ax < 0.0004f) ? ax : r;
}

// ---- kernel 1: VT[o][node] = tanh_xla(3*(E[idx] @ W.T + b)), k-major out ----
__global__ __launch_bounds__(256) void k_embed(
    const int* __restrict__ gidx,
    const float* __restrict__ E1, const float* __restrict__ E2,
    const float* __restrict__ W1, const float* __restrict__ b1,
    const float* __restrict__ W2, const float* __restrict__ b2,
    float* __restrict__ VT1, float* __restrict__ VT2,
    uint32_t* __restrict__ viol)
{
    __shared__ float W1s[DIM][DIM + 1];
    __shared__ float W2s[DIM][DIM + 1];
    __shared__ float E1s[4][DIM];
    __shared__ float E2s[4][DIM];
    __shared__ float T1[DIM][5];
    __shared__ float T2[DIM][5];
    const int t = threadIdx.x;
    if (blockIdx.x == 0 && t == 0) *viol = 0u;   // stream-ordered before k_score
    for (int i = t; i < DIM * DIM; i += 256) {
        W1s[i >> 6][i & 63] = W1[i];
        W2s[i >> 6][i & 63] = W2[i];
    }
    const int rbase = blockIdx.x * 4;
    for (int i = t; i < 4 * DIM; i += 256) {
        const int r = i >> 6, k = i & 63;
        const int g = gidx[rbase + r];
        E1s[r][k] = E1[(size_t)g * DIM + k];
        E2s[r][k] = E2[(size_t)g * DIM + k];
    }
    __syncthreads();
    const int o = t & 63, rs = t >> 6;
    float m1 = 0.0f, m2 = 0.0f;
    #pragma unroll
    for (int k = 0; k < DIM; ++k) {
        m1 = fmaf(E1s[rs][k], W1s[o][k], m1);
        m2 = fmaf(E2s[rs][k], W2s[o][k], m2);
    }
    T1[o][rs] = tanh_xla(3.0f * (m1 + b1[o]));
    T2[o][rs] = tanh_xla(3.0f * (m2 + b2[o]));
    __syncthreads();
    const int oo = t >> 2, rr = t & 3;       // transposed store
    VT1[(size_t)oo * NN + rbase + rr] = T1[oo][rr];
    VT2[(size_t)oo * NN + rbase + rr] = T2[oo][rr];
}

// ---- kernel 2: A = relu(tanh_xla(3*(M1 - M2))), bit-exact XLA chains. ----
// Best-measured config (r14): 256 thr, BK2=16 dbuf global_load_lds, scalar
// fmaf. Plateau at ~159us / 2 waves/SIMD (128-acc register wall; r7/r12
// spill, r16 wave-split all worse). Adds saturation-violation check for
// k_topk's prefix fast path (any A-entry with bits > Cb -> flag).
__global__ __launch_bounds__(256) void k_score(
    const float* __restrict__ VT1, const float* __restrict__ VT2,
    float* __restrict__ out, uint32_t* __restrict__ viol)
{
    // decode upper-tri linear id -> (bi, bj), bi <= bj
    const int L = blockIdx.x;
    int bi = (int)(64.5f - sqrtf(fmaf(-2.0f, (float)L, 64.5f * 64.5f)));
    while (bi * NTB - (bi * (bi - 1)) / 2 > L) --bi;
    while ((bi + 1) * NTB - ((bi + 1) * bi) / 2 <= L) ++bi;
    const int bj = bi + (L - (bi * NTB - (bi * (bi - 1)) / 2));

    // [buf][array][k][col]; arrays: 0=A1(V1,I) 1=A2(V2,I) 2=B1(V1,J) 3=B2(V2,J)
    __shared__ __align__(16) float lds[2][4][BK2][TILE];   // 64 KB

    const int t = threadIdx.x;
    const int tx = t & 15;                     // col groups: tx*4 and 64+tx*4
    const int ty = t >> 4;                     // 8 rows each: ty*8..+7
    const int Ibase = bi * TILE, Jbase = bj * TILE;

    // staging role: wave w fills array w; 8 DMA/wave/chunk (1 KB each)
    const int w = t >> 6, l = t & 63;
    const float* vt = (w & 1) ? VT2 : VT1;
    const int cbase = (w & 2) ? Jbase : Ibase;
    const int srow = (l >> 5);                 // 0/1
    const int scol = (l & 31) * 4;

    float acc1[8][8], acc2[8][8];
    #pragma unroll
    for (int i = 0; i < 8; ++i)
        #pragma unroll
        for (int j = 0; j < 8; ++j) { acc1[i][j] = 0.0f; acc2[i][j] = 0.0f; }

    // prologue fill buf0 with chunk 0
    #pragma unroll
    for (int p = 0; p < 8; ++p) {
        const float* src = vt + (size_t)(2 * p + srow) * NN + cbase + scol;
        __builtin_amdgcn_global_load_lds((AS1 const void*)src,
                                         (AS3 void*)&lds[0][w][2 * p + srow][scol], 16, 0, 0);
    }
    __syncthreads();

    for (int c4 = 0; c4 < 4; ++c4) {           // ascending 16-wide k chunks
        const int cur = c4 & 1;
        if (c4 < 3) {                          // prefetch next chunk into other buf
            const int ckn = (c4 + 1) * BK2;
            #pragma unroll
            for (int p = 0; p < 8; ++p) {
                const float* src = vt + (size_t)(ckn + 2 * p + srow) * NN + cbase + scol;
                __builtin_amdgcn_global_load_lds((AS1 const void*)src,
                                                 (AS3 void*)&lds[cur ^ 1][w][2 * p + srow][scol], 16, 0, 0);
            }
        }
        #pragma unroll 2
        for (int k = 0; k < BK2; ++k) {        // strictly ascending k
            float a1[8], a2[8], c1[8], c2[8];
            *(float4*)&a1[0] = *(const float4*)&lds[cur][0][k][ty * 8];
            *(float4*)&a1[4] = *(const float4*)&lds[cur][0][k][ty * 8 + 4];
            *(float4*)&a2[0] = *(const float4*)&lds[cur][1][k][ty * 8];
            *(float4*)&a2[4] = *(const float4*)&lds[cur][1][k][ty * 8 + 4];
            *(float4*)&c1[0] = *(const float4*)&lds[cur][2][k][tx * 4];
            *(float4*)&c1[4] = *(const float4*)&lds[cur][2][k][tx * 4 + 64];
            *(float4*)&c2[0] = *(const float4*)&lds[cur][3][k][tx * 4];
            *(float4*)&c2[4] = *(const float4*)&lds[cur][3][k][tx * 4 + 64];
            #pragma unroll
            for (int i = 0; i < 8; ++i)
                #pragma unroll
                for (int j = 0; j < 8; ++j) {
                    acc1[i][j] = fmaf(a1[i], c2[j], acc1[i][j]);  // M1: v1_i.v2_j
                    acc2[i][j] = fmaf(a2[i], c1[j], acc2[i][j]);  // M2: v2_i.v1_j
                }
        }
        __syncthreads();                       // next buf ready; cur free to refill
    }

    // epilogue IN-PLACE: acc1 <- wn (normal tile), acc2 <- wm (mirror tile)
    const uint32_t Cb = __float_as_uint(tanh_xla_pos(8.0f));
    uint32_t mx = 0;
    #pragma unroll
    for (int i = 0; i < 8; ++i)
        #pragma unroll
        for (int j = 0; j < 8; ++j) {
            const float aa = acc1[i][j] - acc2[i][j];   // one f32 sub (M1-M2)
            const float tt = tanh_xla_pos(3.0f * fabsf(aa));
            acc1[i][j] = (aa > 0.0f) ? tt : 0.0f;       // relu(tanh(3a))
            acc2[i][j] = (aa < 0.0f) ? tt : 0.0f;       // relu(tanh(-3a))
            const uint32_t u1 = __float_as_uint(acc1[i][j]);
            const uint32_t u2 = __float_as_uint(acc2[i][j]);
            mx = u1 > mx ? u1 : mx;
            mx = u2 > mx ? u2 : mx;
        }
    if (mx > Cb) atomicOr(viol, 1u);           // saturation ceiling violated (never, in practice)
    #pragma unroll
    for (int i = 0; i < 8; ++i) {
        const int gi = Ibase + ty * 8 + i;
        *(float4*)&out[(size_t)gi * NN + Jbase + tx * 4] =
            make_float4(acc1[i][0], acc1[i][1], acc1[i][2], acc1[i][3]);
        *(float4*)&out[(size_t)gi * NN + Jbase + 64 + tx * 4] =
            make_float4(acc1[i][4], acc1[i][5], acc1[i][6], acc1[i][7]);
    }
    if (bi != bj) {
        #pragma unroll
        for (int j = 0; j < 8; ++j) {
            const int gj = Jbase + tx * 4 + (j >> 2) * 64 + (j & 3);
            float4* p = (float4*)&out[(size_t)gj * NN + Ibase + ty * 8];
            p[0] = make_float4(acc2[0][j], acc2[1][j], acc2[2][j], acc2[3][j]);
            p[1] = make_float4(acc2[4][j], acc2[5][j], acc2[6][j], acc2[7][j]);
        }
    }
}

// ---- kernel 3: exact stable top-32 per row ----
// PREFIX fast path: saturated rows' top-32 = 32 smallest-index entries with
// bits == Cb; kept values are exactly C. Scan 1024-col chunks until 32 C's
// found (usually 1 chunk = 4KB read), write C/0 for scanned chunks, pure
// zero-fill for the rest (NO read). 536 MB -> ~300 MB traffic. Safety:
// k_score's viol flag (any entry > Cb) and found<32 both divert to the
// full radix fallback BEFORE any write (row data still intact).
__global__ __launch_bounds__(256) void k_topk(float* __restrict__ out,
                                              const uint32_t* __restrict__ viol)
{
    __shared__ uint32_t hist[2048];            // fallback only, 8 KB
    __shared__ uint32_t waveTot[4];
    __shared__ int xs_s;
    __shared__ uint32_t bc_bin, bc_ca, bc_m, bc_flag;

    const int row = blockIdx.x;
    const int t = threadIdx.x;
    const int wid = t >> 6, lane = t & 63;
    float* rp = out + (size_t)row * NN;
    const uint32_t Cb = __float_as_uint(tanh_xla_pos(8.0f));
    const float Cf = __uint_as_float(Cb);

    if (*viol == 0u) {
        uint32_t kb = 0;                       // 4 C-bits per chunk, 8 chunks
        int found = 0;
        int mchunk = -1;
        for (int ch = 0; ch < 8; ++ch) {
            const float4 f = *(const float4*)&rp[ch * 1024 + t * 4];
            uint32_t nib = 0;
            if (__float_as_uint(f.x) == Cb) nib |= 1u;
            if (__float_as_uint(f.y) == Cb) nib |= 2u;
            if (__float_as_uint(f.z) == Cb) nib |= 4u;
            if (__float_as_uint(f.w) == Cb) nib |= 8u;
            kb |= nib << (ch * 4);
            const uint32_t c = (uint32_t)__popc(nib);
            uint32_t inc = c;                  // wave inclusive prefix
            #pragma unroll
            for (int d = 1; d < 64; d <<= 1) {
                const uint32_t o = (uint32_t)__shfl_up((int)inc, d, 64);
                if (lane >= d) inc += o;
            }
            if (lane == 63) waveTot[wid] = inc;
            __syncthreads();
            const int tot = (int)(waveTot[0] + waveTot[1] + waveTot[2] + waveTot[3]);
            if (found + tot >= KSEL) {         // 32nd C-entry is in this chunk
                const uint32_t need2 = (uint32_t)(KSEL - found);
                uint32_t woff = 0;
                for (int w2 = 0; w2 < wid; ++w2) woff += waveTot[w2];
                const uint32_t pre = woff + inc - c;   // exclusive prefix
                if (pre < need2 && need2 <= pre + c) {
                    uint32_t nn = need2 - pre, mm = nib; int bit = 0;
                    for (uint32_t q2 = 0; q2 < nn; ++q2) { bit = __ffs(mm) - 1; mm &= mm - 1u; }
                    xs_s = ch * 1024 + t * 4 + bit;    // gi of the 32nd entry
                }
                __syncthreads();
                mchunk = ch;
                break;
            }
            found += tot;
            __syncthreads();                   // waveTot reused next chunk
        }
        if (mchunk >= 0) {
            const int xs = xs_s;
            for (int ch = 0; ch <= mchunk; ++ch) {     // masked write of scanned chunks
                const uint32_t nib = (kb >> (ch * 4)) & 0xFu;
                float w[4];
                #pragma unroll
                for (int e = 0; e < 4; ++e) {
                    const int gi = ch * 1024 + t * 4 + e;
                    w[e] = (((nib >> e) & 1u) && gi <= xs) ? Cf : 0.0f;
                }
                *(float4*)&rp[ch * 1024 + t * 4] = make_float4(w[0], w[1], w[2], w[3]);
            }
            const float4 z4 = make_float4(0.f, 0.f, 0.f, 0.f);
            for (int ch = mchunk + 1; ch < 8; ++ch)    // pure zero-fill, no read
                *(float4*)&rp[ch * 1024 + t * 4] = z4;
            return;
        }
        // fell through all chunks with <32 C-entries: row untouched -> fallback
    }

    // ---- fallback: full-row 44-bit radix select, key=(A_bits<<13)|(8191-col) ----
    float v[32];
    #pragma unroll
    for (int s = 0; s < 8; ++s) {
        const float4 f = *(const float4*)&rp[(s * 256 + t) * 4];
        v[s*4+0] = f.x; v[s*4+1] = f.y; v[s*4+2] = f.z; v[s*4+3] = f.w;
    }
    if (t == 0) bc_flag = 0;
    __syncthreads();

    uint64_t prefix = 0, thr = 0;
    int need = KSEL;
    bool done = false;   // block-uniform at all times

    for (int pass = 0; pass < 4; ++pass) {
        const int shift = 33 - 11 * pass;
        {   // zero hist: 512 uint4 / 256 thr = 2 each
            const uint4 z = make_uint4(0u, 0u, 0u, 0u);
            uint4* hp = (uint4*)hist;
            hp[t] = z; hp[256 + t] = z;
        }
        __syncthreads();
        #pragma unroll
        for (int s = 0; s < 8; ++s) {
            #pragma unroll
            for (int e = 0; e < 4; ++e) {
                const uint32_t vb = __float_as_uint(v[s*4+e]);
                if (vb == 0u) continue;
                const int gi = s * 1024 + t * 4 + e;
                const uint64_t key = ((uint64_t)vb << 13) | (uint32_t)(8191 - gi);
                if ((key >> (shift + 11)) == prefix)
                    atomicAdd(&hist[(uint32_t)((key >> shift) & 2047u)], 1u);
            }
        }
        __syncthreads();
        uint32_t m[8]; uint32_t tot = 0;
        #pragma unroll
        for (int i = 0; i < 8; ++i) {
            m[i] = hist[t * 8 + i];
            tot += m[i];
        }
        uint32_t ssum = tot;   // inclusive suffix-sum within wave
        #pragma unroll
        for (int d = 1; d < 64; d <<= 1) {
            const uint32_t o = __shfl_down(ssum, d, 64);
            if (lane + d < 64) ssum += o;
        }
        if (lane == 0) waveTot[wid] = ssum;
        __syncthreads();
        {
            uint32_t above = 0;
            for (int w2 = wid + 1; w2 < 4; ++w2) above += waveTot[w2];
            if (pass == 0) {
                const uint32_t totalAll = waveTot[0] + waveTot[1] + waveTot[2] + waveTot[3];
                if (totalAll < (uint32_t)need && t == 0) bc_flag = 1;  // <32 positives
            }
            uint32_t c = (ssum - tot) + above;       // count in bins above my chunk
            #pragma unroll
            for (int i = 7; i >= 0; --i) {           // walk my 8 bins top-down
                if (c < (uint32_t)need && (uint32_t)need <= c + m[i]) {
                    bc_bin = (uint32_t)(t * 8 + i);  // unique winner
                    bc_ca  = c;
                    bc_m   = m[i];
                }
                c += m[i];
            }
        }
        __syncthreads();
        if (bc_flag) { thr = 1; done = true; }       // keep all positives
        else {
            prefix = (prefix << 11) | (uint64_t)bc_bin;
            need  -= (int)bc_ca;
            if ((uint32_t)need == bc_m) {            // whole bin selected exactly
                thr = prefix << shift;               // bin lower bound
                done = true;
            } else if (pass == 3) { thr = prefix; done = true; }
        }
        if (done) break;                              // block-uniform
        __syncthreads();
    }

    #pragma unroll
    for (int s = 0; s < 8; ++s) {
        float w[4];
        #pragma unroll
        for (int e = 0; e < 4; ++e) {
            const float a = v[s*4+e];
            const uint32_t vb = __float_as_uint(a);
            const int gi = s * 1024 + t * 4 + e;
            const uint64_t key = ((uint64_t)vb << 13) | (uint32_t)(8191 - gi);
            w[e] = (vb != 0u && key >= thr) ? a : 0.f;
        }
        *(float4*)&rp[(s * 256 + t) * 4] = make_float4(w[0], w[1], w[2], w[3]);
    }
}

extern "C" void kernel_launch(void* const* d_in, const int* in_sizes, int n_in,
                              void* d_out, int out_size, void* d_ws, size_t ws_size,
                              hipStream_t stream)
{
    const int*   idx = (const int*)  d_in[0];
    const float* E1  = (const float*)d_in[1];
    const float* E2  = (const float*)d_in[2];
    const float* W1  = (const float*)d_in[3];
    const float* b1  = (const float*)d_in[4];
    const float* W2  = (const float*)d_in[5];
    const float* b2  = (const float*)d_in[6];
    float* out = (float*)d_out;
    float* VT1 = (float*)d_ws;                 // 2 MB, [64][8192] k-major
    float* VT2 = VT1 + (size_t)NN * DIM;       // 2 MB
    uint32_t* viol = (uint32_t*)(VT2 + (size_t)NN * DIM);

    k_embed<<<NN / 4, 256, 0, stream>>>(idx, E1, E2, W1, b1, W2, b2, VT1, VT2, viol);
    k_score<<<NTRI, 256, 0, stream>>>(VT1, VT2, out, viol);
    k_topk<<<NN, 256, 0, stream>>>(out, viol);
}

// Round 18
// 280.482 us; speedup vs baseline: 1.3039x; 1.3039x over previous
//
#include <hip/hip_runtime.h>
#include <stdint.h>
#include <math.h>

#define NN 8192
#define DIM 64
#define KSEL 32
#define BK2 16
#define TILE 128
#define NTB (NN / TILE)          // 64 tiles per side
#define NTRI ((NTB * (NTB + 1)) / 2)   // 2080 upper-tri blocks

#define AS1 __attribute__((address_space(1)))
#define AS3 __attribute__((address_space(3)))

// ---- XLA/Eigen f32 tanh rational approximation (bit-exact emulation) ----
__device__ __forceinline__ float tanh_xla(float x) {
    const float kClamp = 7.90531110763549805f;
    float xc = fminf(fmaxf(x, -kClamp), kClamp);
    float x2 = xc * xc;
    float p = -2.76076847742355e-16f;
    p = fmaf(x2, p, 2.00018790482477e-13f);
    p = fmaf(x2, p, -8.60467152213735e-11f);
    p = fmaf(x2, p, 5.12229709037114e-08f);
    p = fmaf(x2, p, 1.48572235717979e-05f);
    p = fmaf(x2, p, 6.37261928875436e-04f);
    p = fmaf(x2, p, 4.89352455891786e-03f);
    p = xc * p;
    float q = 1.19825839466702e-06f;
    q = fmaf(x2, q, 1.18534705686654e-04f);
    q = fmaf(x2, q, 2.26843463243900e-03f);
    q = fmaf(x2, q, 4.89352518554385e-03f);
    float r = p / q;
    return (fabsf(x) < 0.0004f) ? x : r;
}
// positive-input variant (ax >= 0), same bits as tanh_xla(ax)
__device__ __forceinline__ float tanh_xla_pos(float ax) {
    const float kClamp = 7.90531110763549805f;
    float xc = fminf(ax, kClamp);
    float x2 = xc * xc;
    float p = -2.76076847742355e-16f;
    p = fmaf(x2, p, 2.00018790482477e-13f);
    p = fmaf(x2, p, -8.60467152213735e-11f);
    p = fmaf(x2, p, 5.12229709037114e-08f);
    p = fmaf(x2, p, 1.48572235717979e-05f);
    p = fmaf(x2, p, 6.37261928875436e-04f);
    p = fmaf(x2, p, 4.89352455891786e-03f);
    p = xc * p;
    float q = 1.19825839466702e-06f;
    q = fmaf(x2, q, 1.18534705686654e-04f);
    q = fmaf(x2, q, 2.26843463243900e-03f);
    q = fmaf(x2, q, 4.89352518554385e-03f);
    float r = p / q;
    return (ax < 0.0004f) ? ax : r;
}

// ---- kernel 1: VT[o][node] = tanh_xla(3*(E[idx] @ W.T + b)), k-major out ----
__global__ __launch_bounds__(256) void k_embed(
    const int* __restrict__ gidx,
    const float* __restrict__ E1, const float* __restrict__ E2,
    const float* __restrict__ W1, const float* __restrict__ b1,
    const float* __restrict__ W2, const float* __restrict__ b2,
    float* __restrict__ VT1, float* __restrict__ VT2)
{
    __shared__ float W1s[DIM][DIM + 1];
    __shared__ float W2s[DIM][DIM + 1];
    __shared__ float E1s[4][DIM];
    __shared__ float E2s[4][DIM];
    __shared__ float T1[DIM][5];
    __shared__ float T2[DIM][5];
    const int t = threadIdx.x;
    for (int i = t; i < DIM * DIM; i += 256) {
        W1s[i >> 6][i & 63] = W1[i];
        W2s[i >> 6][i & 63] = W2[i];
    }
    const int rbase = blockIdx.x * 4;
    for (int i = t; i < 4 * DIM; i += 256) {
        const int r = i >> 6, k = i & 63;
        const int g = gidx[rbase + r];
        E1s[r][k] = E1[(size_t)g * DIM + k];
        E2s[r][k] = E2[(size_t)g * DIM + k];
    }
    __syncthreads();
    const int o = t & 63, rs = t >> 6;
    float m1 = 0.0f, m2 = 0.0f;
    #pragma unroll
    for (int k = 0; k < DIM; ++k) {
        m1 = fmaf(E1s[rs][k], W1s[o][k], m1);
        m2 = fmaf(E2s[rs][k], W2s[o][k], m2);
    }
    T1[o][rs] = tanh_xla(3.0f * (m1 + b1[o]));
    T2[o][rs] = tanh_xla(3.0f * (m2 + b2[o]));
    __syncthreads();
    const int oo = t >> 2, rr = t & 3;       // transposed store
    VT1[(size_t)oo * NN + rbase + rr] = T1[oo][rr];
    VT2[(size_t)oo * NN + rbase + rr] = T2[oo][rr];
}

// ---- kernel 2: A = relu(tanh_xla(3*(M1 - M2))), bit-exact XLA chains. ----
// Best-measured config (r14, 158.8us): 256 thr, BK2=16 dbuf global_load_lds,
// scalar fmaf, in-place epilogue. Latency-plateau at 2 waves/SIMD from the
// 128-accumulator register wall (r7/r12 spill; r11 BK=8, r13 full-unroll,
// r15 pk_fma, r16 wave-split all neutral-to-worse).
__global__ __launch_bounds__(256) void k_score(
    const float* __restrict__ VT1, const float* __restrict__ VT2,
    float* __restrict__ out)
{
    // decode upper-tri linear id -> (bi, bj), bi <= bj
    const int L = blockIdx.x;
    int bi = (int)(64.5f - sqrtf(fmaf(-2.0f, (float)L, 64.5f * 64.5f)));
    while (bi * NTB - (bi * (bi - 1)) / 2 > L) --bi;
    while ((bi + 1) * NTB - ((bi + 1) * bi) / 2 <= L) ++bi;
    const int bj = bi + (L - (bi * NTB - (bi * (bi - 1)) / 2));

    // [buf][array][k][col]; arrays: 0=A1(V1,I) 1=A2(V2,I) 2=B1(V1,J) 3=B2(V2,J)
    __shared__ __align__(16) float lds[2][4][BK2][TILE];   // 64 KB

    const int t = threadIdx.x;
    const int tx = t & 15;                     // col groups: tx*4 and 64+tx*4
    const int ty = t >> 4;                     // 8 rows each: ty*8..+7
    const int Ibase = bi * TILE, Jbase = bj * TILE;

    // staging role: wave w fills array w; 8 DMA/wave/chunk (1 KB each)
    const int w = t >> 6, l = t & 63;
    const float* vt = (w & 1) ? VT2 : VT1;
    const int cbase = (w & 2) ? Jbase : Ibase;
    const int srow = (l >> 5);                 // 0/1
    const int scol = (l & 31) * 4;

    float acc1[8][8], acc2[8][8];
    #pragma unroll
    for (int i = 0; i < 8; ++i)
        #pragma unroll
        for (int j = 0; j < 8; ++j) { acc1[i][j] = 0.0f; acc2[i][j] = 0.0f; }

    // prologue fill buf0 with chunk 0
    #pragma unroll
    for (int p = 0; p < 8; ++p) {
        const float* src = vt + (size_t)(2 * p + srow) * NN + cbase + scol;
        __builtin_amdgcn_global_load_lds((AS1 const void*)src,
                                         (AS3 void*)&lds[0][w][2 * p + srow][scol], 16, 0, 0);
    }
    __syncthreads();

    for (int c4 = 0; c4 < 4; ++c4) {           // ascending 16-wide k chunks
        const int cur = c4 & 1;
        if (c4 < 3) {                          // prefetch next chunk into other buf
            const int ckn = (c4 + 1) * BK2;
            #pragma unroll
            for (int p = 0; p < 8; ++p) {
                const float* src = vt + (size_t)(ckn + 2 * p + srow) * NN + cbase + scol;
                __builtin_amdgcn_global_load_lds((AS1 const void*)src,
                                                 (AS3 void*)&lds[cur ^ 1][w][2 * p + srow][scol], 16, 0, 0);
            }
        }
        #pragma unroll 2
        for (int k = 0; k < BK2; ++k) {        // strictly ascending k
            float a1[8], a2[8], c1[8], c2[8];
            *(float4*)&a1[0] = *(const float4*)&lds[cur][0][k][ty * 8];
            *(float4*)&a1[4] = *(const float4*)&lds[cur][0][k][ty * 8 + 4];
            *(float4*)&a2[0] = *(const float4*)&lds[cur][1][k][ty * 8];
            *(float4*)&a2[4] = *(const float4*)&lds[cur][1][k][ty * 8 + 4];
            *(float4*)&c1[0] = *(const float4*)&lds[cur][2][k][tx * 4];
            *(float4*)&c1[4] = *(const float4*)&lds[cur][2][k][tx * 4 + 64];
            *(float4*)&c2[0] = *(const float4*)&lds[cur][3][k][tx * 4];
            *(float4*)&c2[4] = *(const float4*)&lds[cur][3][k][tx * 4 + 64];
            #pragma unroll
            for (int i = 0; i < 8; ++i)
                #pragma unroll
                for (int j = 0; j < 8; ++j) {
                    acc1[i][j] = fmaf(a1[i], c2[j], acc1[i][j]);  // M1: v1_i.v2_j
                    acc2[i][j] = fmaf(a2[i], c1[j], acc2[i][j]);  // M2: v2_i.v1_j
                }
        }
        __syncthreads();                       // next buf ready; cur free to refill
    }

    // epilogue IN-PLACE: acc1 <- wn (normal tile), acc2 <- wm (mirror tile)
    #pragma unroll
    for (int i = 0; i < 8; ++i)
        #pragma unroll
        for (int j = 0; j < 8; ++j) {
            const float aa = acc1[i][j] - acc2[i][j];   // one f32 sub (M1-M2)
            const float tt = tanh_xla_pos(3.0f * fabsf(aa));
            acc1[i][j] = (aa > 0.0f) ? tt : 0.0f;       // relu(tanh(3a))
            acc2[i][j] = (aa < 0.0f) ? tt : 0.0f;       // relu(tanh(-3a))
        }
    #pragma unroll
    for (int i = 0; i < 8; ++i) {
        const int gi = Ibase + ty * 8 + i;
        *(float4*)&out[(size_t)gi * NN + Jbase + tx * 4] =
            make_float4(acc1[i][0], acc1[i][1], acc1[i][2], acc1[i][3]);
        *(float4*)&out[(size_t)gi * NN + Jbase + 64 + tx * 4] =
            make_float4(acc1[i][4], acc1[i][5], acc1[i][6], acc1[i][7]);
    }
    if (bi != bj) {
        #pragma unroll
        for (int j = 0; j < 8; ++j) {
            const int gj = Jbase + tx * 4 + (j >> 2) * 64 + (j & 3);
            float4* p = (float4*)&out[(size_t)gj * NN + Ibase + ty * 8];
            p[0] = make_float4(acc2[0][j], acc2[1][j], acc2[2][j], acc2[3][j]);
            p[1] = make_float4(acc2[4][j], acc2[5][j], acc2[6][j], acc2[7][j]);
        }
    }
}

// ---- kernel 3: exact stable top-32 per row, 44-bit radix select ----
// Best-measured variant (r6/r10, ~100-115us): 4-replica hist (atomic
// contention /4), uniform early-break, whole-bin exact exit. r17's prefix
// "fast path" was built on an unverified saturation assumption and
// regressed to 215us (FETCH showed ~4 chunks scanned + radix re-read).
// key = (A_bits << 13) | (8191 - col): value desc then index asc = lax.top_k.
__global__ __launch_bounds__(256) void k_topk(float* __restrict__ out)
{
    __shared__ uint32_t hist[4][2048];
    __shared__ uint32_t waveTot[4];
    __shared__ uint32_t bc_bin, bc_ca, bc_m, bc_flag;

    const int row = blockIdx.x;
    const int t = threadIdx.x;
    const int wid = t >> 6, lane = t & 63;
    float* rp = out + (size_t)row * NN;

    float v[32];
    #pragma unroll
    for (int s = 0; s < 8; ++s) {
        const float4 f = *(const float4*)&rp[(s * 256 + t) * 4];
        v[s*4+0] = f.x; v[s*4+1] = f.y; v[s*4+2] = f.z; v[s*4+3] = f.w;
    }
    if (t == 0) bc_flag = 0;

    uint64_t prefix = 0, thr = 0;
    int need = KSEL;
    bool done = false;   // block-uniform at all times

    for (int pass = 0; pass < 4; ++pass) {
        const int shift = 33 - 11 * pass;
        {   // zero hist: 2048 uint4 / 256 thr = 8 each
            const uint4 z = make_uint4(0u, 0u, 0u, 0u);
            uint4* hp = (uint4*)hist;
            #pragma unroll
            for (int i = 0; i < 8; ++i) hp[i * 256 + t] = z;
        }
        __syncthreads();
        #pragma unroll
        for (int s = 0; s < 8; ++s) {
            #pragma unroll
            for (int e = 0; e < 4; ++e) {
                const uint32_t vb = __float_as_uint(v[s*4+e]);
                if (vb == 0u) continue;
                const int gi = s * 1024 + t * 4 + e;
                const uint64_t key = ((uint64_t)vb << 13) | (uint32_t)(8191 - gi);
                if ((key >> (shift + 11)) == prefix)
                    atomicAdd(&hist[wid][(uint32_t)((key >> shift) & 2047u)], 1u);
            }
        }
        __syncthreads();
        uint32_t m[8]; uint32_t tot = 0;
        #pragma unroll
        for (int i = 0; i < 8; ++i) {
            const int b = t * 8 + i;
            m[i] = hist[0][b] + hist[1][b] + hist[2][b] + hist[3][b];
            tot += m[i];
        }
        uint32_t ssum = tot;   // inclusive suffix-sum within wave
        #pragma unroll
        for (int d = 1; d < 64; d <<= 1) {
            const uint32_t o = __shfl_down(ssum, d, 64);
            if (lane + d < 64) ssum += o;
        }
        if (lane == 0) waveTot[wid] = ssum;
        __syncthreads();
        {
            uint32_t above = 0;
            for (int w2 = wid + 1; w2 < 4; ++w2) above += waveTot[w2];
            if (pass == 0) {
                const uint32_t totalAll = waveTot[0] + waveTot[1] + waveTot[2] + waveTot[3];
                if (totalAll < (uint32_t)need && t == 0) bc_flag = 1;  // <32 positives
            }
            uint32_t c = (ssum - tot) + above;       // count in bins above my chunk
            #pragma unroll
            for (int i = 7; i >= 0; --i) {           // walk my 8 bins top-down
                if (c < (uint32_t)need && (uint32_t)need <= c + m[i]) {
                    bc_bin = (uint32_t)(t * 8 + i);  // unique winner
                    bc_ca  = c;
                    bc_m   = m[i];
                }
                c += m[i];
            }
        }
        __syncthreads();
        if (bc_flag) { thr = 1; done = true; }       // keep all positives
        else {
            prefix = (prefix << 11) | (uint64_t)bc_bin;
            need  -= (int)bc_ca;
            if ((uint32_t)need == bc_m) {            // whole bin selected exactly
                thr = prefix << shift;               // bin lower bound
                done = true;
            } else if (pass == 3) { thr = prefix; done = true; }
        }
        if (done) break;                              // block-uniform
        __syncthreads();
    }

    #pragma unroll
    for (int s = 0; s < 8; ++s) {
        float w[4];
        #pragma unroll
        for (int e = 0; e < 4; ++e) {
            const float a = v[s*4+e];
            const uint32_t vb = __float_as_uint(a);
            const int gi = s * 1024 + t * 4 + e;
            const uint64_t key = ((uint64_t)vb << 13) | (uint32_t)(8191 - gi);
            w[e] = (vb != 0u && key >= thr) ? a : 0.f;
        }
        *(float4*)&rp[(s * 256 + t) * 4] = make_float4(w[0], w[1], w[2], w[3]);
    }
}

extern "C" void kernel_launch(void* const* d_in, const int* in_sizes, int n_in,
                              void* d_out, int out_size, void* d_ws, size_t ws_size,
                              hipStream_t stream)
{
    const int*   idx = (const int*)  d_in[0];
    const float* E1  = (const float*)d_in[1];
    const float* E2  = (const float*)d_in[2];
    const float* W1  = (const float*)d_in[3];
    const float* b1  = (const float*)d_in[4];
    const float* W2  = (const float*)d_in[5];
    const float* b2  = (const float*)d_in[6];
    float* out = (float*)d_out;
    float* VT1 = (float*)d_ws;                 // 2 MB, [64][8192] k-major
    float* VT2 = VT1 + (size_t)NN * DIM;       // 2 MB

    k_embed<<<NN / 4, 256, 0, stream>>>(idx, E1, E2, W1, b1, W2, b2, VT1, VT2);
    k_score<<<NTRI, 256, 0, stream>>>(VT1, VT2, out);
    k_topk<<<NN, 256, 0, stream>>>(out);
}